// Round 5
// baseline (926.400 us; speedup 1.0000x reference)
//
#include <hip/hip_runtime.h>

// GroupBimodalCSRPool on MI355X.
//   feats = [x_proj, x_proj - mn[seg], x_proj - mx[seg], rsqrt(size)]  (V,97)
//   h = feats @ W1 + b1 -> BN(global batch stats) -> ReLU
//   C = h @ Ws + bs -> scaled segment softmax -> weighted pool of x_mod -> gate
// Group sizes in [1,7].
//
// R3: split pass A (k1a group-parallel base, k1b element-parallel matvec,
//     block-partial BN stats -- killed the 476us atomic/shuffle stall).
// R5: k3 was ~280us vs ~105us floor (latency + uniform VALU). New k2b_attn
//     precomputes gate-folded attention A'[v,c]; k3 is now a pure 2-group-
//     per-wave gather-weighted stream with static unrolling.

#define K1A_BLOCK 256
#define K1B_BLOCK 256
#define K1B_MAXBLOCKS 2048

__device__ inline float4 bfly32_sum(float4 p) {
#pragma unroll
    for (int m = 16; m >= 1; m >>= 1) {
        p.x += __shfl_xor(p.x, m, 32);
        p.y += __shfl_xor(p.y, m, 32);
        p.z += __shfl_xor(p.z, m, 32);
        p.w += __shfl_xor(p.w, m, 32);
    }
    return p;
}

// k1a: per-group min/max + base vector; writes base into hbuf[v,4] for each
// element of the group. One 32-lane half-wave per group; lane = proj dim.
__global__ __launch_bounds__(K1A_BLOCK) void k1a_base(
    const float* __restrict__ xp, const int* __restrict__ csr,
    const float* __restrict__ W1, const float* __restrict__ b1,
    float* __restrict__ hbuf, int N)
{
    const int lane32 = threadIdx.x & 31;
    const int halfIdx = threadIdx.x >> 5;
    const int halves = K1A_BLOCK >> 5;
    const int gstride = gridDim.x * halves;
    const int d = lane32;
    const float4 wb = *(const float4*)(W1 + (32 + d) * 4);
    const float4 wc = *(const float4*)(W1 + (64 + d) * 4);
    const float4 w96 = *(const float4*)(W1 + 96 * 4);
    const float4 b1v = *(const float4*)(b1);

    for (int g = blockIdx.x * halves + halfIdx; g < N; g += gstride) {
        const int r0 = csr[g];
        const int size = csr[g + 1] - r0;
        const float pnum = rsqrtf((float)size);

        float mn = 1e30f, mx = -1e30f;
#pragma unroll
        for (int j = 0; j < 8; ++j) {
            if (j < size) {
                const float x = xp[(size_t)(r0 + j) * 32 + d];
                mn = fminf(mn, x);
                mx = fmaxf(mx, x);
            }
        }

        float4 pb = make_float4(-(mn * wb.x + mx * wc.x), -(mn * wb.y + mx * wc.y),
                                -(mn * wb.z + mx * wc.z), -(mn * wb.w + mx * wc.w));
        pb = bfly32_sum(pb);

        const int c = lane32 & 3;
        const float basec = (c == 0) ? pb.x + b1v.x + pnum * w96.x
                          : (c == 1) ? pb.y + b1v.y + pnum * w96.y
                          : (c == 2) ? pb.z + b1v.z + pnum * w96.z
                                     : pb.w + b1v.w + pnum * w96.w;
        if (lane32 < 4 * size) hbuf[(size_t)4 * r0 + lane32] = basec;
    }
}

// k1b: per-element matvec, thread = (element, channel), weights in VGPRs,
// BN stats as per-block partials (no atomics).
__global__ __launch_bounds__(K1B_BLOCK) void k1b_mat(
    const float* __restrict__ xp, const float* __restrict__ W1,
    float* __restrict__ hbuf, float* __restrict__ partials, int V)
{
    const int tid = threadIdx.x;
    const int c = tid & 3;
    float wcol[32];
#pragma unroll
    for (int d = 0; d < 32; ++d)
        wcol[d] = W1[d * 4 + c] + W1[(32 + d) * 4 + c] + W1[(64 + d) * 4 + c];

    const int slot = (blockIdx.x * K1B_BLOCK + tid) >> 2;
    const int nslots = (gridDim.x * K1B_BLOCK) >> 2;
    float s = 0.f, ss = 0.f;
    for (int v = slot; v < V; v += nslots) {
        const float* row = xp + (size_t)v * 32;
        float acc = hbuf[(size_t)4 * v + c];
#pragma unroll
        for (int d = 0; d < 32; d += 4) {
            const float4 x4 = *(const float4*)(row + d);
            acc += x4.x * wcol[d] + x4.y * wcol[d + 1]
                 + x4.z * wcol[d + 2] + x4.w * wcol[d + 3];
        }
        hbuf[(size_t)4 * v + c] = acc;
        s += acc;
        ss += acc * acc;
    }

    __shared__ float rs[K1B_BLOCK], rss[K1B_BLOCK];
    rs[tid] = s; rss[tid] = ss;
    __syncthreads();
#pragma unroll
    for (int off = K1B_BLOCK / 2; off >= 4; off >>= 1) {
        if (tid < off) { rs[tid] += rs[tid + off]; rss[tid] += rss[tid + off]; }
        __syncthreads();
    }
    if (tid < 4) {
        partials[blockIdx.x * 8 + tid] = rs[tid];
        partials[blockIdx.x * 8 + 4 + tid] = rss[tid];
    }
}

// k2: reduce partials -> BN scale/shift.
__global__ void k2_bnfold(const float* __restrict__ partials, int nb,
                          const float* __restrict__ gamma,
                          const float* __restrict__ beta,
                          float* __restrict__ scsh, float invV)
{
    __shared__ float red[256];
    const int tid = threadIdx.x;
    const int c = tid & 7;
    float s = 0.f;
    for (int b = tid >> 3; b < nb; b += 32) s += partials[b * 8 + c];
    red[tid] = s;
    __syncthreads();
    for (int off = 128; off >= 8; off >>= 1) {
        if (tid < off) red[tid] += red[tid + off];
        __syncthreads();
    }
    if (tid < 4) {
        const float mean = red[tid] * invV;
        float var = red[4 + tid] * invV - mean * mean;
        var = fmaxf(var, 0.f);
        const float sc = gamma[tid] * rsqrtf(var + 1e-5f);
        scsh[tid] = sc;
        scsh[4 + tid] = beta[tid] - mean * sc;
    }
}

// k2b: per-element gate-folded attention A'[v,c] = softmax_c(v) * G[g,c].
// Half-wave per group; lane role (j = lane>>2, c = lane&3); per-lane scalar
// score chain for its channel only. Writes x_seen too.
__global__ __launch_bounds__(256) void k2b_attn(
    const float* __restrict__ hbuf, const int* __restrict__ csr,
    const float* __restrict__ Ws, const float* __restrict__ bs,
    const float* __restrict__ gw, const float* __restrict__ gb,
    const float* __restrict__ scsh, float* __restrict__ aprime,
    float* __restrict__ outseen, int N)
{
    const int lane32 = threadIdx.x & 31;
    const int g = blockIdx.x * 8 + (threadIdx.x >> 5);
    if (g >= N) return;
    const int c = lane32 & 3;
    const int jmine = lane32 >> 2;

    const float4 sc = *(const float4*)(scsh);
    const float4 sh = *(const float4*)(scsh + 4);
    const float wc0 = Ws[0 * 4 + c], wc1 = Ws[1 * 4 + c];
    const float wc2 = Ws[2 * 4 + c], wc3 = Ws[3 * 4 + c];
    const float bsc = bs[c], gwc = gw[c], gbc = gb[c];

    const int r0 = csr[g];
    const int size = csr[g + 1] - r0;
    const float rs = rsqrtf((float)size);

    float cj[8];
    float cmax = -1e30f;
#pragma unroll
    for (int j = 0; j < 8; ++j) {
        if (j < size) {
            const float4 hv = *(const float4*)(hbuf + (size_t)4 * (r0 + j));
            const float v0 = fmaxf(hv.x * sc.x + sh.x, 0.f);
            const float v1 = fmaxf(hv.y * sc.y + sh.y, 0.f);
            const float v2 = fmaxf(hv.z * sc.z + sh.z, 0.f);
            const float v3 = fmaxf(hv.w * sc.w + sh.w, 0.f);
            cj[j] = v0 * wc0 + v1 * wc1 + v2 * wc2 + v3 * wc3 + bsc;
            cmax = fmaxf(cmax, cj[j]);
        }
    }
    float denom = 1e-12f;
#pragma unroll
    for (int j = 0; j < 8; ++j) {
        if (j < size) {
            cj[j] = expf((cj[j] - cmax) * rs);
            denom += cj[j];
        }
    }
    const float G = tanhf(fmaxf(gwc * cmax + gbc, 0.f));
    const float scale = G / denom;

    float aj = 0.f;
#pragma unroll
    for (int j = 0; j < 8; ++j)
        if (j == jmine) aj = cj[j];
    if (lane32 < 4 * size) aprime[(size_t)4 * r0 + lane32] = aj * scale;
    if (lane32 == 0) outseen[g] = (size > 0) ? 1.0f : 0.0f;
}

// k3: pure gather-weighted stream. 2 groups per wave, static unroll,
// lane owns 2 channels (float2).
__global__ __launch_bounds__(256) void k3_pool(
    const float* __restrict__ xmod, const float* __restrict__ aprime,
    const int* __restrict__ csr, float* __restrict__ outp, int N)
{
    const int lane = threadIdx.x & 63;
    const int waveId = blockIdx.x * 4 + (threadIdx.x >> 6);
    const int g0 = waveId * 2;
    const int g1 = g0 + 1;
    if (g0 >= N) return;
    const int gi = lane >> 4;
    const bool hasb = (g1 < N);

    const int r0a = csr[g0];
    const int sza = csr[g0 + 1] - r0a;
    int r0b = 0, szb = 0;
    if (hasb) { r0b = csr[g1]; szb = csr[g1 + 1] - r0b; }

    float aa[8], ab[8];
#pragma unroll
    for (int j = 0; j < 8; ++j) {
        aa[j] = (j < sza) ? aprime[(size_t)4 * (r0a + j) + gi] : 0.f;
        ab[j] = (hasb && j < szb) ? aprime[(size_t)4 * (r0b + j) + gi] : 0.f;
    }

    float2 acca = make_float2(0.f, 0.f), accb = make_float2(0.f, 0.f);
#pragma unroll
    for (int j = 0; j < 8; ++j) {
        if (j < sza) {
            const float2 x = *(const float2*)(xmod + (size_t)(r0a + j) * 128 + 2 * lane);
            acca.x += x.x * aa[j];
            acca.y += x.y * aa[j];
        }
    }
#pragma unroll
    for (int j = 0; j < 8; ++j) {
        if (hasb && j < szb) {
            const float2 x = *(const float2*)(xmod + (size_t)(r0b + j) * 128 + 2 * lane);
            accb.x += x.x * ab[j];
            accb.y += x.y * ab[j];
        }
    }
    *(float2*)(outp + (size_t)g0 * 128 + 2 * lane) = acca;
    if (hasb) *(float2*)(outp + (size_t)g1 * 128 + 2 * lane) = accb;
}

extern "C" void kernel_launch(void* const* d_in, const int* in_sizes, int n_in,
                              void* d_out, int out_size, void* d_ws, size_t ws_size,
                              hipStream_t stream) {
    const float* xmod  = (const float*)d_in[0];
    const float* xproj = (const float*)d_in[1];
    const int*   csr   = (const int*)d_in[2];
    const float* W1    = (const float*)d_in[3];
    const float* b1    = (const float*)d_in[4];
    const float* gamma = (const float*)d_in[5];
    const float* beta  = (const float*)d_in[6];
    const float* Ws    = (const float*)d_in[7];
    const float* bs    = (const float*)d_in[8];
    const float* gw    = (const float*)d_in[9];
    const float* gb    = (const float*)d_in[10];

    const int V = in_sizes[0] / 128;
    const int N = in_sizes[2] - 1;

    float* outp = (float*)d_out;
    float* outseen = outp + (size_t)N * 128;

    // ws layout: hbuf[V*4] | partials[K1B_MAXBLOCKS*8] | scsh[8] | aprime[V*4]
    float* hbuf = (float*)d_ws;
    float* partials = hbuf + (size_t)V * 4;
    float* scsh = partials + (size_t)K1B_MAXBLOCKS * 8;
    float* aprime = scsh + 8;

    const int halves1 = K1A_BLOCK / 32;
    int blocks1a = (N + halves1 - 1) / halves1;
    if (blocks1a > 4096) blocks1a = 4096;
    k1a_base<<<blocks1a, K1A_BLOCK, 0, stream>>>(xproj, csr, W1, b1, hbuf, N);

    const int elemsPerBlock = K1B_BLOCK / 4;
    int blocks1b = (V + elemsPerBlock - 1) / elemsPerBlock;
    if (blocks1b > K1B_MAXBLOCKS) blocks1b = K1B_MAXBLOCKS;
    k1b_mat<<<blocks1b, K1B_BLOCK, 0, stream>>>(xproj, W1, hbuf, partials, V);

    k2_bnfold<<<1, 256, 0, stream>>>(partials, blocks1b, gamma, beta, scsh,
                                     1.0f / (float)V);

    int blocks2b = (N + 7) / 8;
    k2b_attn<<<blocks2b, 256, 0, stream>>>(hbuf, csr, Ws, bs, gw, gb, scsh,
                                           aprime, outseen, N);

    int blocks3 = (N + 7) / 8;   // 4 waves/block, 2 groups/wave
    k3_pool<<<blocks3, 256, 0, stream>>>(xmod, aprime, csr, outp, N);
}